// Round 19
// baseline (83.829 us; speedup 1.0000x reference)
//
#include <hip/hip_runtime.h>
#include <hip/hip_fp16.h>
#include <math.h>

#define Q_TOT 10000
#define NVIEW 6
#define NTOK  2442
#define HP_   37
#define WP_   66
#define CD_   768
#define CC_   256

typedef __attribute__((ext_vector_type(8))) short bf16x8;
typedef __attribute__((ext_vector_type(4))) float f32x4;

__device__ inline unsigned f2bf(float f) {
    unsigned u = __builtin_bit_cast(unsigned, f);
    unsigned r = u + 0x7FFFu + ((u >> 16) & 1u);
    return r >> 16;
}

__device__ __forceinline__ void glds16(const void* g, void* l) {
    __builtin_amdgcn_global_load_lds(
        (const __attribute__((address_space(1))) unsigned int*)g,
        (__attribute__((address_space(3))) unsigned int*)l,
        16, 0, 0);
}

// ---------------- fused prep: w2 2-rows/block (384) + opw/ref2d/concat (395) ----------
__global__ __launch_bounds__(256) void prep_all(const float* __restrict__ vp_w,
                                                const float* __restrict__ proj_w,
                                                const float* __restrict__ opw,
                                                const float* __restrict__ l2i,
                                                const float* __restrict__ so_w,
                                                const float* __restrict__ so_b,
                                                const float* __restrict__ aw_w,
                                                const float* __restrict__ aw_b,
                                                const float* __restrict__ wview,
                                                unsigned short* __restrict__ W2b,
                                                unsigned short* __restrict__ opwb,
                                                float* __restrict__ ref2d,
                                                unsigned short* __restrict__ WQb,
                                                float* __restrict__ bqp,
                                                float* __restrict__ vwn) {
    int b0 = blockIdx.x, tid = threadIdx.x;
    if (b0 < 384) {
        int o2 = (b0 / 3) * 2;
        int c = (b0 % 3) * 256 + tid;
        __shared__ float vps[2][256];
        vps[0][tid] = vp_w[(size_t)o2 * 256 + tid];
        vps[1][tid] = vp_w[(size_t)(o2 + 1) * 256 + tid];
        __syncthreads();
        float acc0 = 0.f, acc1 = 0.f;
#pragma unroll 8
        for (int o = 0; o < 256; ++o) {
            float pw = proj_w[(size_t)o * CD_ + c];
            acc0 += vps[0][o] * pw;
            acc1 += vps[1][o] * pw;
        }
        W2b[(size_t)o2 * CD_ + c] = (unsigned short)f2bf(acc0);
        W2b[(size_t)(o2 + 1) * CD_ + c] = (unsigned short)f2bf(acc1);
        return;
    }
    int b = b0 - 384;
    if (b < 32) {
        int i = b * 256 + tid;                 // < 8192
        float4 a = *(const float4*)(opw + (size_t)i * 8);
        float4 c4 = *(const float4*)(opw + (size_t)i * 8 + 4);
        uint4 o;
        o.x = f2bf(a.x) | (f2bf(a.y) << 16);
        o.y = f2bf(a.z) | (f2bf(a.w) << 16);
        o.z = f2bf(c4.x) | (f2bf(c4.y) << 16);
        o.w = f2bf(c4.z) | (f2bf(c4.w) << 16);
        *(uint4*)(opwb + (size_t)i * 8) = o;
    } else if (b < 267) {
        int idx = (b - 32) * 256 + tid;
        if (idx < NVIEW * Q_TOT) {
            int v = idx / Q_TOT, q = idx % Q_TOT;
            int wq = q % 100, hq = q / 100;
            float wx = (wq + 0.5f) * 1.024f - 51.2f;
            float wy = (hq + 0.5f) * 1.024f - 51.2f;
            const float* L = l2i + v * 16;
            float L0=L[0],L1=L[1],L2=L[2],L3=L[3],L4=L[4],L5=L[5],L6=L[6],L7=L[7];
            float L8=L[8],L9=L[9],L10=L[10],L11=L[11];
            float sw = 0.f, sx = 0.f, sy = 0.f;
#pragma unroll
            for (int d = 0; d < 4; ++d) {
                float zs = (0.5f + (float)d * (7.0f / 3.0f)) * 0.125f;
                float wz = zs * 8.0f - 5.0f;
                float c0 = L0 * wx + L1 * wy + L2 * wz + L3;
                float c1 = L4 * wx + L5 * wy + L6 * wz + L7;
                float c2 = L8 * wx + L9 * wy + L10 * wz + L11;
                bool bm = c2 > 1e-5f;
                float dc = fmaxf(c2, 1e-5f);
                float u  = (c0 / dc) * 0.5775f;
                float vv = (c1 / dc) * 0.5775f;
                bool in_img = (u >= 0.f) && (u <= 923.f) && (vv >= 0.f) && (vv <= 517.f);
                bool valid = bm && in_img;
                float refx = fminf(fmaxf(u / 923.0f, 0.f), 1.f);
                float refy = fminf(fmaxf(vv / 517.0f, 0.f), 1.f);
                float w = valid ? 1.0f : 1e-6f;
                sw += w; sx += refx * w; sy += refy * w;
            }
            float den = fmaxf(sw, 1e-6f);
            ref2d[(size_t)idx * 2 + 0] = sx / den;
            ref2d[(size_t)idx * 2 + 1] = sy / den;
        }
    } else {
        int row = b - 267, col = tid;
        float v = (row < 64) ? so_w[row * 256 + col] : (row < 96 ? aw_w[(row - 64) * 256 + col] : 0.f);
        WQb[row * 256 + col] = (unsigned short)f2bf(v);
        if (row == 0 && col < 128) bqp[col] = (col < 64) ? so_b[col] : (col < 96 ? aw_b[col - 64] : 0.f);
        if (row == 1 && col == 0) {
            float sp[6], swv = 0.f;
#pragma unroll
            for (int vv = 0; vv < NVIEW; ++vv) {
                float x = wview[vv];
                float s = (x > 20.f) ? x : log1pf(expf(x));
                sp[vv] = s; swv += s;
            }
            float inv = 1.0f / fmaxf(swv, 1e-6f);
#pragma unroll
            for (int vv = 0; vv < NVIEW; ++vv) vwn[vv] = sp[vv] * inv;
            vwn[6] = swv * inv;
            vwn[7] = 0.f;
        }
    }
}

// ======== val GEMM: fp32-A glds, 64x64 tile, 2 buffers, counted vmcnt(6), fp16 out ====
template <int KT>
__device__ __forceinline__ void gemm_glds32A(char* lds,
                                             const float* __restrict__ Af,
                                             const unsigned short* __restrict__ Bw,
                                             const float* __restrict__ bias,
                                             unsigned short* __restrict__ Ch,
                                             int M, int bid, int nwg) {
    constexpr int K = KT * 64;
    int tid = threadIdx.x;
    int wid = tid >> 6, lane = tid & 63;

    int qd = nwg >> 3, r = nwg & 7;
    int xcd = bid & 7, seq = bid >> 3;
    int wgid = (xcd < r) ? (xcd * (qd + 1) + seq) : (r * (qd + 1) + (xcd - r) * qd + seq);
    int mt = wgid >> 2;
    int nt = wgid & 3;
    int m0 = mt * 64, n0 = nt * 64;

    int lr = lane & 15, lq = lane >> 4;

    f32x4 acc[4];
#pragma unroll
    for (int j = 0; j < 4; ++j) acc[j] = (f32x4)(0.f);

#define STAGE(BI, KTI) do {                                                           \
    char* bufA = lds + (BI) * 24576;                                                  \
    char* bufB = bufA + 16384;                                                        \
    _Pragma("unroll")                                                                 \
    for (int i_ = 0; i_ < 4; ++i_) {                                                  \
        int L_ = tid + (i_ << 8);                                                     \
        int row_ = L_ >> 4, ch_ = L_ & 15;                                            \
        int gr_ = m0 + row_; gr_ = gr_ < M ? gr_ : M - 1;                             \
        glds16((const char*)Af + (size_t)gr_ * (K * 4) + ((KTI) << 8) + ((ch_ ^ (row_ & 7)) << 4), \
               bufA + (L_ << 4));                                                     \
    }                                                                                 \
    _Pragma("unroll")                                                                 \
    for (int i_ = 0; i_ < 2; ++i_) {                                                  \
        int L_ = tid + (i_ << 8);                                                     \
        int row_ = L_ >> 3, c_ = L_ & 7;                                              \
        glds16((const char*)Bw + (size_t)(n0 + row_) * (K * 2) + ((KTI) << 7) + ((c_ ^ (row_ & 7)) << 4), \
               bufB + (L_ << 4));                                                     \
    }                                                                                 \
} while (0)

#define GMFMA(BI) do {                                                                \
    char* bufA = lds + (BI) * 24576;                                                  \
    char* bufB = bufA + 16384;                                                        \
    _Pragma("unroll")                                                                 \
    for (int s_ = 0; s_ < 2; ++s_) {                                                  \
        int cg_ = (s_ << 2) + lq;                                                     \
        int arow_ = (wid << 4) + lr;                                                  \
        f32x4 a0_ = *(f32x4*)(bufA + arow_ * 256 + ((((cg_ << 1))     ^ (arow_ & 7)) << 4)); \
        f32x4 a1_ = *(f32x4*)(bufA + arow_ * 256 + ((((cg_ << 1) | 1) ^ (arow_ & 7)) << 4)); \
        unsigned w0_, w1_, w2_, w3_;                                                  \
        asm("v_cvt_pk_bf16_f32 %0, %1, %2" : "=v"(w0_) : "v"(a0_[0]), "v"(a0_[1]));   \
        asm("v_cvt_pk_bf16_f32 %0, %1, %2" : "=v"(w1_) : "v"(a0_[2]), "v"(a0_[3]));   \
        asm("v_cvt_pk_bf16_f32 %0, %1, %2" : "=v"(w2_) : "v"(a1_[0]), "v"(a1_[1]));   \
        asm("v_cvt_pk_bf16_f32 %0, %1, %2" : "=v"(w3_) : "v"(a1_[2]), "v"(a1_[3]));   \
        bf16x8 af_ = __builtin_bit_cast(bf16x8, make_uint4(w0_, w1_, w2_, w3_));      \
        _Pragma("unroll")                                                             \
        for (int j_ = 0; j_ < 4; ++j_) {                                              \
            int brow_ = (j_ << 4) + lr;                                               \
            bf16x8 bf_ = *(bf16x8*)(bufB + brow_ * 128 + ((cg_ ^ (brow_ & 7)) << 4)); \
            acc[j_] = __builtin_amdgcn_mfma_f32_16x16x32_bf16(af_, bf_, acc[j_], 0, 0, 0); \
        }                                                                             \
    }                                                                                 \
} while (0)

    STAGE(0, 0);
    if (KT > 1) STAGE(1, 1);
#pragma unroll
    for (int kt = 0; kt < KT; ++kt) {
        if (kt + 1 < KT) {
            asm volatile("s_waitcnt vmcnt(6)" ::: "memory");
        } else {
            asm volatile("s_waitcnt vmcnt(0)" ::: "memory");
        }
        __builtin_amdgcn_s_barrier();
        __builtin_amdgcn_sched_barrier(0);
        GMFMA(kt & 1);
        __builtin_amdgcn_sched_barrier(0);
        __builtin_amdgcn_s_barrier();
        if (kt + 2 < KT) STAGE(kt & 1, kt + 2);
    }

    int mb = m0 + (wid << 4) + (lq << 2);
#pragma unroll
    for (int j = 0; j < 4; ++j) {
        int n = n0 + (j << 4) + lr;
        float bn = bias[n];
#pragma unroll
        for (int e = 0; e < 4; ++e) {
            int m = mb + e;
            if (m < M) Ch[(size_t)m * 256 + n] =
                __builtin_bit_cast(unsigned short, __float2half(acc[j][e] + bn));
        }
    }
#undef STAGE
#undef GMFMA
}

// ======== glds GEMM (bf16 A): 64x64, 3-buffer counted vmcnt(4) — out path ========
template <int MODE, int KT>
__device__ __forceinline__ void gemm_glds(char* lds,
                                          const unsigned short* __restrict__ Ah,
                                          const unsigned short* __restrict__ Bw,
                                          const float* __restrict__ bias,
                                          const float* __restrict__ resid,
                                          const float* __restrict__ wview,
                                          void* __restrict__ Cptr,
                                          int M, int nt_shift, int bid, int nwg) {
    constexpr int K = KT * 64;
    int tid = threadIdx.x;
    int wid = tid >> 6, lane = tid & 63;

    int qd = nwg >> 3, r = nwg & 7;
    int xcd = bid & 7, seq = bid >> 3;
    int wgid = (xcd < r) ? (xcd * (qd + 1) + seq) : (r * (qd + 1) + (xcd - r) * qd + seq);
    int mt = wgid >> nt_shift;
    int nt = wgid & ((1 << nt_shift) - 1);
    int m0 = mt * 64, n0 = nt * 64;

    int lr = lane & 15, lq = lane >> 4;
    float* Cf = (float*)Cptr;

    f32x4 acc[4];
#pragma unroll
    for (int j = 0; j < 4; ++j) acc[j] = (f32x4)(0.f);

#define STAGE(BI, KTI) do {                                                           \
    char* buf = lds + (BI) * 16384;                                                   \
    int k0b = (KTI) << 7;                                                             \
    _Pragma("unroll")                                                                 \
    for (int i_ = 0; i_ < 2; ++i_) {                                                  \
        int L_ = tid + (i_ << 8);                                                     \
        int row_ = L_ >> 3, c_ = L_ & 7;                                              \
        glds16((const char*)Ah + (size_t)(m0 + row_) * (K * 2) + k0b + ((c_ ^ (row_ & 7)) << 4), \
               buf + (L_ << 4));                                                      \
    }                                                                                 \
    _Pragma("unroll")                                                                 \
    for (int i_ = 0; i_ < 2; ++i_) {                                                  \
        int L_ = tid + (i_ << 8);                                                     \
        int row_ = L_ >> 3, c_ = L_ & 7;                                              \
        glds16((const char*)Bw + (size_t)(n0 + row_) * (K * 2) + k0b + ((c_ ^ (row_ & 7)) << 4), \
               buf + 8192 + (L_ << 4));                                               \
    }                                                                                 \
} while (0)

#define GMFMA(BI) do {                                                                \
    char* Abb = lds + (BI) * 16384;                                                   \
    char* Bbb = Abb + 8192;                                                           \
    _Pragma("unroll")                                                                 \
    for (int s_ = 0; s_ < 2; ++s_) {                                                  \
        int chunk_ = (s_ << 2) + lq;                                                  \
        int arow_ = (wid << 4) + lr;                                                  \
        bf16x8 af_ = *(bf16x8*)(Abb + arow_ * 128 + ((chunk_ ^ (arow_ & 7)) << 4));   \
        _Pragma("unroll")                                                             \
        for (int j_ = 0; j_ < 4; ++j_) {                                              \
            int brow_ = (j_ << 4) + lr;                                               \
            bf16x8 bf_ = *(bf16x8*)(Bbb + brow_ * 128 + ((chunk_ ^ (brow_ & 7)) << 4)); \
            acc[j_] = __builtin_amdgcn_mfma_f32_16x16x32_bf16(af_, bf_, acc[j_], 0, 0, 0); \
        }                                                                             \
    }                                                                                 \
} while (0)

    STAGE(0, 0);
    if (KT > 1) STAGE(1, 1);
#pragma unroll
    for (int kt = 0; kt < KT; ++kt) {
        if (kt + 1 < KT) {
            asm volatile("s_waitcnt vmcnt(4)" ::: "memory");
        } else {
            asm volatile("s_waitcnt vmcnt(0)" ::: "memory");
        }
        __builtin_amdgcn_s_barrier();
        __builtin_amdgcn_sched_barrier(0);
        if (kt + 2 < KT) STAGE((kt + 2) % 3, kt + 2);
        GMFMA(kt % 3);
        __builtin_amdgcn_sched_barrier(0);
    }

    {
        float s = 0.f;
#pragma unroll
        for (int v = 0; v < 6; ++v) {
            float x = wview[v];
            s += (x > 20.f) ? x : log1pf(expf(x));
        }
        float f = s / fmaxf(s, 1e-6f);
        int mb = m0 + (wid << 4) + (lq << 2);
#pragma unroll
        for (int j = 0; j < 4; ++j) {
            int n = n0 + (j << 4) + lr;
            float bn = bias[n];
            if (mb + 4 <= M) {
                float4 o;
                float* oo = (float*)&o;
#pragma unroll
                for (int e = 0; e < 4; ++e)
                    oo[e] = acc[j][e] + f * (bn + resid[(size_t)(mb + e) * 256 + n]);
                *(float4*)(Cf + (size_t)n * M + mb) = o;
            } else {
#pragma unroll
                for (int e = 0; e < 4; ++e) {
                    int m = mb + e;
                    if (m < M) Cf[(size_t)n * M + m] = acc[j][e] + f * (bn + resid[(size_t)m * 256 + n]);
                }
            }
        }
    }
#undef STAGE
#undef GMFMA
}

// ---------------- qout GEMM body: fp32 A reg-staged (64x64, 2-stage) ----------------
template <int KT>
__device__ __forceinline__ void gemm_f32A(char* base0, char* base1,
                                          const float* __restrict__ Af,
                                          const unsigned short* __restrict__ Bw,
                                          const float* __restrict__ bias,
                                          float* __restrict__ Cf,
                                          int M, int nt_shift, int bid, int nwg) {
    constexpr int K = KT * 64;
    int tid = threadIdx.x;
    int wid = tid >> 6, lane = tid & 63;

    int qd = nwg >> 3, r = nwg & 7;
    int xcd = bid & 7, seq = bid >> 3;
    int wgid = (xcd < r) ? (xcd * (qd + 1) + seq) : (r * (qd + 1) + (xcd - r) * qd + seq);
    int mt = wgid >> nt_shift;
    int nt = wgid & ((1 << nt_shift) - 1);
    int m0 = mt * 64, n0 = nt * 64;

    int lr = lane & 15, lq = lane >> 4;
    int arow_s = tid >> 4;
    int ac4 = tid & 15;

    f32x4 acc[4];
#pragma unroll
    for (int j = 0; j < 4; ++j) acc[j] = (f32x4)(0.f);

    float4 aF[2][4];
    uint4  bR[2][2];
    const float4 zf4 = make_float4(0.f, 0.f, 0.f, 0.f);

#define QLOADG(S, KTI) do {                                                           \
    int k0 = (KTI) << 6;                                                              \
    _Pragma("unroll")                                                                 \
    for (int p_ = 0; p_ < 4; ++p_) {                                                  \
        int row_ = p_ * 16 + arow_s;                                                  \
        bool av_ = (m0 + row_) < M;                                                   \
        aF[S][p_] = av_ ? *(const float4*)(Af + (size_t)(m0 + row_) * K + k0 + ac4 * 4) : zf4; \
    }                                                                                 \
    _Pragma("unroll")                                                                 \
    for (int i_ = 0; i_ < 2; ++i_) {                                                  \
        int s_ = tid + (i_ << 8);                                                     \
        int row_ = s_ >> 3, c_ = s_ & 7;                                              \
        bR[S][i_] = *(const uint4*)(Bw + (size_t)(n0 + row_) * K + k0 + c_ * 8);      \
    }                                                                                 \
} while (0)

#define QTOLDS(S, PB) do {                                                            \
    char* Abb = (PB) ? base1 : base0;                                                 \
    _Pragma("unroll")                                                                 \
    for (int p_ = 0; p_ < 4; ++p_) {                                                  \
        int row_ = p_ * 16 + arow_s;                                                  \
        const float* f_ = (const float*)&aF[S][p_];                                   \
        uint2 w_;                                                                     \
        w_.x = f2bf(f_[0]) | (f2bf(f_[1]) << 16);                                     \
        w_.y = f2bf(f_[2]) | (f2bf(f_[3]) << 16);                                     \
        int byte_ = row_ * 128 + (((ac4 >> 1) ^ (row_ & 7)) << 4) + ((ac4 & 1) << 3); \
        *(uint2*)(Abb + byte_) = w_;                                                  \
    }                                                                                 \
    char* Bbb = Abb + 8192;                                                           \
    _Pragma("unroll")                                                                 \
    for (int i_ = 0; i_ < 2; ++i_) {                                                  \
        int s_ = tid + (i_ << 8);                                                     \
        int row_ = s_ >> 3, c_ = s_ & 7;                                              \
        *(uint4*)(Bbb + row_ * 128 + ((c_ ^ (row_ & 7)) << 4)) = bR[S][i_];           \
    }                                                                                 \
} while (0)

#define QMFMAS(PB) do {                                                               \
    char* Abb = (PB) ? base1 : base0;                                                 \
    char* Bbb = Abb + 8192;                                                           \
    _Pragma("unroll")                                                                 \
    for (int s_ = 0; s_ < 2; ++s_) {                                                  \
        int chunk_ = (s_ << 2) + lq;                                                  \
        int arow_ = (wid << 4) + lr;                                                  \
        bf16x8 af_ = *(bf16x8*)(Abb + arow_ * 128 + ((chunk_ ^ (arow_ & 7)) << 4));   \
        _Pragma("unroll")                                                             \
        for (int j_ = 0; j_ < 4; ++j_) {                                              \
            int brow_ = (j_ << 4) + lr;                                               \
            bf16x8 bf_ = *(bf16x8*)(Bbb + brow_ * 128 + ((chunk_ ^ (brow_ & 7)) << 4)); \
            acc[j_] = __builtin_amdgcn_mfma_f32_16x16x32_bf16(af_, bf_, acc[j_], 0, 0, 0); \
        }                                                                             \
    }                                                                                 \
} while (0)

    QLOADG(0, 0);
#pragma unroll
    for (int kt = 0; kt < KT; ++kt) {
        if (kt + 1 < KT) QLOADG((kt + 1) & 1, kt + 1);
        QTOLDS(kt & 1, kt & 1);
        __builtin_amdgcn_sched_barrier(0);
        asm volatile("s_waitcnt lgkmcnt(0)" ::: "memory");
        __builtin_amdgcn_s_barrier();
        __builtin_amdgcn_sched_barrier(0);
        QMFMAS(kt & 1);
    }

    int mb = m0 + (wid << 4) + (lq << 2);
#pragma unroll
    for (int j = 0; j < 4; ++j) {
        int n = n0 + (j << 4) + lr;
        if (n >= 96) continue;
        float bn = bias[n];
#pragma unroll
        for (int e = 0; e < 4; ++e) {
            int m = mb + e;
            if (m < M) Cf[(size_t)m * 96 + n] = acc[j][e] + bn;
        }
    }
#undef QLOADG
#undef QTOLDS
#undef QMFMAS
}

// val (916 blocks, fp32-A glds, fp16 out) + qout (314 blocks, reg-staged)
__global__ __launch_bounds__(256, 3) void dual_gemm(const float* __restrict__ lt,
                                                    const unsigned short* __restrict__ W2b,
                                                    const float* __restrict__ vpb,
                                                    unsigned short* __restrict__ valH,
                                                    const float* __restrict__ bqq,
                                                    const unsigned short* __restrict__ WQb,
                                                    const float* __restrict__ bqp,
                                                    float* __restrict__ qout) {
    __shared__ char lds[49152];
    if (blockIdx.x < 916)
        gemm_glds32A<12>(lds, lt, W2b, vpb, valH, 14652, blockIdx.x, 916);
    else
        gemm_f32A<4>(lds, lds + 16384, bqq, WQb, bqp, qout, Q_TOT, 1, blockIdx.x - 916, 314);
}

__global__ __launch_bounds__(256, 3) void out_gemm(const unsigned short* __restrict__ sampavgB,
                                                   const unsigned short* __restrict__ opwb,
                                                   const float* __restrict__ opb,
                                                   const float* __restrict__ bqq,
                                                   const float* __restrict__ wview,
                                                   float* __restrict__ out) {
    __shared__ char lds[49152];
    gemm_glds<1, 4>(lds, sampavgB, opwb, opb, bqq, wview,
                    (void*)out, Q_TOT, 2, blockIdx.x, gridDim.x);
}

// ---------------- deformable sampling: fp16 table, dwordx2 gathers, pk_fma_f16 ------
__global__ __launch_bounds__(256) void sample_kernel(const unsigned short* __restrict__ valH,
                                                     const float* __restrict__ ref2d,
                                                     const float* __restrict__ qout,
                                                     const float* __restrict__ vwn,
                                                     unsigned short* __restrict__ sampavgB) {
    __shared__ uint4  sOff[4 * 240];
    __shared__ uint4  sWh[4 * 240];   // 4x packed half2 (w,w) per corner
    __shared__ float4 sAt[4 * 8];
    __shared__ float  sVw[8];
    int tid = threadIdx.x;
    int qb = blockIdx.x * 4;

    if (tid < 32) {
        int ql = tid >> 3, h = tid & 7;
        const float* qo = qout + (size_t)(qb + ql) * 96 + 64 + h * 4;
        float a0 = qo[0], a1 = qo[1], a2 = qo[2], a3 = qo[3];
        float mx = fmaxf(fmaxf(a0, a1), fmaxf(a2, a3));
        float e0 = __expf(a0 - mx), e1 = __expf(a1 - mx), e2 = __expf(a2 - mx), e3 = __expf(a3 - mx);
        float inv = 1.0f / (e0 + e1 + e2 + e3);
        sAt[ql * 8 + h] = make_float4(e0 * inv, e1 * inv, e2 * inv, e3 * inv);
        if (tid < 8) sVw[tid] = vwn[tid < 6 ? tid : 0];
    }
    __syncthreads();

#pragma unroll
    for (int t = tid; t < 768; t += 256) {
        int ql = t / 192;
        int rem = t - ql * 192;
        int v = rem >> 5;
        int h = (rem >> 2) & 7;
        int p = rem & 3;
        int q = qb + ql;
        const float* qo = qout + (size_t)q * 96;
        float ox = qo[h * 8 + 2 * p];
        float oy = qo[h * 8 + 2 * p + 1];
        float at = ((const float*)&sAt[ql * 8 + h])[p];
        float scale = at * sVw[v];

        float rx = ref2d[(size_t)(v * Q_TOT + q) * 2 + 0];
        float ry = ref2d[(size_t)(v * Q_TOT + q) * 2 + 1];
        float x = rx * 66.0f + ox - 0.5f;
        float y = ry * 37.0f + oy - 0.5f;
        float xf = floorf(x), yf = floorf(y);
        float fx = x - xf, fy = y - yf;
        int xi = (int)xf, yi = (int)yf;

        float cw[4] = { (1.f - fx) * (1.f - fy), fx * (1.f - fy), (1.f - fx) * fy, fx * fy };
        unsigned off[4];
#pragma unroll
        for (int cyi = 0; cyi < 2; ++cyi) {
#pragma unroll
            for (int cxi = 0; cxi < 2; ++cxi) {
                int cx = xi + cxi, cy = yi + cyi;
                bool ok = (cx >= 0) && (cx < WP_) && (cy >= 0) && (cy < HP_);
                int ccx = cx < 0 ? 0 : (cx > WP_ - 1 ? WP_ - 1 : cx);
                int ccy = cy < 0 ? 0 : (cy > HP_ - 1 ? HP_ - 1 : cy);
                int c_ = cyi * 2 + cxi;
                off[c_] = (unsigned)((v * NTOK + ccy * WP_ + ccx) << 9);  // 512 B/token (fp16)
                cw[c_] = ok ? cw[c_] * scale : 0.f;
            }
        }
        int slot = ql * 240 + v * 40 + h * 5 + p;
        sOff[slot] = make_uint4(off[0], off[1], off[2], off[3]);
        unsigned hw0 = (unsigned)__builtin_bit_cast(unsigned short, __float2half(cw[0]));
        unsigned hw1 = (unsigned)__builtin_bit_cast(unsigned short, __float2half(cw[1]));
        unsigned hw2 = (unsigned)__builtin_bit_cast(unsigned short, __float2half(cw[2]));
        unsigned hw3 = (unsigned)__builtin_bit_cast(unsigned short, __float2half(cw[3]));
        sWh[slot] = make_uint4(hw0 | (hw0 << 16), hw1 | (hw1 << 16),
                               hw2 | (hw2 << 16), hw3 | (hw3 << 16));
    }
    __syncthreads();

    int ql = tid >> 6;
    int lane = tid & 63;
    int h = lane >> 3, d4 = (lane & 7) << 2;
    unsigned coff = (unsigned)((h * 32 + d4) << 1);
    const char* vbase = (const char*)valH;
    __half2 a01 = __halves2half2(__float2half(0.f), __float2half(0.f));
    __half2 a23 = a01;
#pragma unroll
    for (int v = 0; v < NVIEW; ++v) {
#pragma unroll
        for (int p = 0; p < 4; ++p) {
            int slot = ql * 240 + v * 40 + h * 5 + p;
            uint4 off = sOff[slot];
            uint4 wh = sWh[slot];
            uint2 r0 = *(const uint2*)(vbase + (off.x + coff));
            uint2 r1 = *(const uint2*)(vbase + (off.y + coff));
            uint2 r2 = *(const uint2*)(vbase + (off.z + coff));
            uint2 r3 = *(const uint2*)(vbase + (off.w + coff));
            __half2 w0 = __builtin_bit_cast(__half2, wh.x);
            __half2 w1 = __builtin_bit_cast(__half2, wh.y);
            __half2 w2 = __builtin_bit_cast(__half2, wh.z);
            __half2 w3 = __builtin_bit_cast(__half2, wh.w);
            a01 = __hfma2(__builtin_bit_cast(__half2, r0.x), w0, a01);
            a23 = __hfma2(__builtin_bit_cast(__half2, r0.y), w0, a23);
            a01 = __hfma2(__builtin_bit_cast(__half2, r1.x), w1, a01);
            a23 = __hfma2(__builtin_bit_cast(__half2, r1.y), w1, a23);
            a01 = __hfma2(__builtin_bit_cast(__half2, r2.x), w2, a01);
            a23 = __hfma2(__builtin_bit_cast(__half2, r2.y), w2, a23);
            a01 = __hfma2(__builtin_bit_cast(__half2, r3.x), w3, a01);
            a23 = __hfma2(__builtin_bit_cast(__half2, r3.y), w3, a23);
        }
    }
    float acc0 = __half2float(__low2half(a01));
    float acc1 = __half2float(__high2half(a01));
    float acc2 = __half2float(__low2half(a23));
    float acc3 = __half2float(__high2half(a23));
    int q = qb + ql;
    unsigned u0 = f2bf(acc0) | (f2bf(acc1) << 16);
    unsigned u1 = f2bf(acc2) | (f2bf(acc3) << 16);
    *(uint2*)(sampavgB + (size_t)q * CC_ + h * 32 + d4) = make_uint2(u0, u1);
}

extern "C" void kernel_launch(void* const* d_in, const int* in_sizes, int n_in,
                              void* d_out, int out_size, void* d_ws, size_t ws_size,
                              hipStream_t stream) {
    const float* lt   = (const float*)d_in[0];
    const float* l2i  = (const float*)d_in[1];
    const float* proj = (const float*)d_in[2];
    const float* bqq  = (const float*)d_in[3];
    const float* wv   = (const float*)d_in[4];
    const float* vpw  = (const float*)d_in[5];
    const float* vpb  = (const float*)d_in[6];
    const float* sow  = (const float*)d_in[7];
    const float* sob  = (const float*)d_in[8];
    const float* aww  = (const float*)d_in[9];
    const float* awb  = (const float*)d_in[10];
    const float* opw  = (const float*)d_in[11];
    const float* opb  = (const float*)d_in[12];
    float* out = (float*)d_out;

    char* ws = (char*)d_ws;
    unsigned short* W2b   = (unsigned short*)(ws);             // 393216
    unsigned short* opwb  = (unsigned short*)(ws + 393216);    // 131072
    unsigned short* WQb   = (unsigned short*)(ws + 524288);    // 65536
    float*          bqp   = (float*)(ws + 589824);             // 512
    float*          vwn   = (float*)(ws + 590336);             // 512
    float*          ref2d = (float*)(ws + 590848);             // 480000
    float*          qout  = (float*)(ws + 1070848);            // 3840000 -> ends 4910848
    unsigned short* valH  = (unsigned short*)(ws + 4910848);   // 7501824 -> ends 12412672
    unsigned short* sampavgB = (unsigned short*)(ws + 12412672); // 5120000 -> ends 17532672

    hipLaunchKernelGGL(prep_all, dim3(779), dim3(256), 0, stream,
                       vpw, proj, opw, l2i, sow, sob, aww, awb, wv,
                       W2b, opwb, ref2d, WQb, bqp, vwn);
    hipLaunchKernelGGL(dual_gemm, dim3(1230), dim3(256), 0, stream,
                       lt, W2b, vpb, valH, bqq, WQb, bqp, qout);
    hipLaunchKernelGGL(sample_kernel, dim3(Q_TOT / 4), dim3(256), 0, stream,
                       valH, ref2d, qout, vwn, sampavgB);
    hipLaunchKernelGGL(out_gemm, dim3(628), dim3(256), 0, stream,
                       sampavgB, opwb, opb, bqq, wv, out);
}

// Round 20
// 82.920 us; speedup vs baseline: 1.0110x; 1.0110x over previous
//
#include <hip/hip_runtime.h>
#include <math.h>

#define Q_TOT 10000
#define NVIEW 6
#define NTOK  2442
#define HP_   37
#define WP_   66
#define CD_   768
#define CC_   256

typedef __attribute__((ext_vector_type(8))) short bf16x8;
typedef __attribute__((ext_vector_type(4))) float f32x4;

__device__ inline unsigned f2bf(float f) {
    unsigned u = __builtin_bit_cast(unsigned, f);
    unsigned r = u + 0x7FFFu + ((u >> 16) & 1u);
    return r >> 16;
}

__device__ __forceinline__ void glds16(const void* g, void* l) {
    __builtin_amdgcn_global_load_lds(
        (const __attribute__((address_space(1))) unsigned int*)g,
        (__attribute__((address_space(3))) unsigned int*)l,
        16, 0, 0);
}

// ---------------- fused prep: w2 2-rows/block (384) + opw/ref2d/concat (395) ----------
__global__ __launch_bounds__(256) void prep_all(const float* __restrict__ vp_w,
                                                const float* __restrict__ proj_w,
                                                const float* __restrict__ opw,
                                                const float* __restrict__ l2i,
                                                const float* __restrict__ so_w,
                                                const float* __restrict__ so_b,
                                                const float* __restrict__ aw_w,
                                                const float* __restrict__ aw_b,
                                                const float* __restrict__ wview,
                                                unsigned short* __restrict__ W2b,
                                                unsigned short* __restrict__ opwb,
                                                float* __restrict__ ref2d,
                                                unsigned short* __restrict__ WQb,
                                                float* __restrict__ bqp,
                                                float* __restrict__ vwn) {
    int b0 = blockIdx.x, tid = threadIdx.x;
    if (b0 < 384) {
        int o2 = (b0 / 3) * 2;
        int c = (b0 % 3) * 256 + tid;
        __shared__ float vps[2][256];
        vps[0][tid] = vp_w[(size_t)o2 * 256 + tid];
        vps[1][tid] = vp_w[(size_t)(o2 + 1) * 256 + tid];
        __syncthreads();
        float acc0 = 0.f, acc1 = 0.f;
#pragma unroll 8
        for (int o = 0; o < 256; ++o) {
            float pw = proj_w[(size_t)o * CD_ + c];
            acc0 += vps[0][o] * pw;
            acc1 += vps[1][o] * pw;
        }
        W2b[(size_t)o2 * CD_ + c] = (unsigned short)f2bf(acc0);
        W2b[(size_t)(o2 + 1) * CD_ + c] = (unsigned short)f2bf(acc1);
        return;
    }
    int b = b0 - 384;
    if (b < 32) {
        int i = b * 256 + tid;                 // < 8192
        float4 a = *(const float4*)(opw + (size_t)i * 8);
        float4 c4 = *(const float4*)(opw + (size_t)i * 8 + 4);
        uint4 o;
        o.x = f2bf(a.x) | (f2bf(a.y) << 16);
        o.y = f2bf(a.z) | (f2bf(a.w) << 16);
        o.z = f2bf(c4.x) | (f2bf(c4.y) << 16);
        o.w = f2bf(c4.z) | (f2bf(c4.w) << 16);
        *(uint4*)(opwb + (size_t)i * 8) = o;
    } else if (b < 267) {
        int idx = (b - 32) * 256 + tid;
        if (idx < NVIEW * Q_TOT) {
            int v = idx / Q_TOT, q = idx % Q_TOT;
            int wq = q % 100, hq = q / 100;
            float wx = (wq + 0.5f) * 1.024f - 51.2f;
            float wy = (hq + 0.5f) * 1.024f - 51.2f;
            const float* L = l2i + v * 16;
            float L0=L[0],L1=L[1],L2=L[2],L3=L[3],L4=L[4],L5=L[5],L6=L[6],L7=L[7];
            float L8=L[8],L9=L[9],L10=L[10],L11=L[11];
            float sw = 0.f, sx = 0.f, sy = 0.f;
#pragma unroll
            for (int d = 0; d < 4; ++d) {
                float zs = (0.5f + (float)d * (7.0f / 3.0f)) * 0.125f;
                float wz = zs * 8.0f - 5.0f;
                float c0 = L0 * wx + L1 * wy + L2 * wz + L3;
                float c1 = L4 * wx + L5 * wy + L6 * wz + L7;
                float c2 = L8 * wx + L9 * wy + L10 * wz + L11;
                bool bm = c2 > 1e-5f;
                float dc = fmaxf(c2, 1e-5f);
                float u  = (c0 / dc) * 0.5775f;
                float vv = (c1 / dc) * 0.5775f;
                bool in_img = (u >= 0.f) && (u <= 923.f) && (vv >= 0.f) && (vv <= 517.f);
                bool valid = bm && in_img;
                float refx = fminf(fmaxf(u / 923.0f, 0.f), 1.f);
                float refy = fminf(fmaxf(vv / 517.0f, 0.f), 1.f);
                float w = valid ? 1.0f : 1e-6f;
                sw += w; sx += refx * w; sy += refy * w;
            }
            float den = fmaxf(sw, 1e-6f);
            ref2d[(size_t)idx * 2 + 0] = sx / den;
            ref2d[(size_t)idx * 2 + 1] = sy / den;
        }
    } else {
        int row = b - 267, col = tid;
        float v = (row < 64) ? so_w[row * 256 + col] : (row < 96 ? aw_w[(row - 64) * 256 + col] : 0.f);
        WQb[row * 256 + col] = (unsigned short)f2bf(v);
        if (row == 0 && col < 128) bqp[col] = (col < 64) ? so_b[col] : (col < 96 ? aw_b[col - 64] : 0.f);
        if (row == 1 && col == 0) {
            float sp[6], swv = 0.f;
#pragma unroll
            for (int vv = 0; vv < NVIEW; ++vv) {
                float x = wview[vv];
                float s = (x > 20.f) ? x : log1pf(expf(x));
                sp[vv] = s; swv += s;
            }
            float inv = 1.0f / fmaxf(swv, 1e-6f);
#pragma unroll
            for (int vv = 0; vv < NVIEW; ++vv) vwn[vv] = sp[vv] * inv;
            vwn[6] = swv * inv;
            vwn[7] = 0.f;
        }
    }
}

// ======== val GEMM: fp32-A glds, 64x64 tile, 2 buffers, counted vmcnt(6) ========
// Per buffer: A fp32 16KB [64 rows x 16 chunks, chunk^=(row&7)] + B bf16 8KB.
// Consume: 2x ds_read_b128 fp32 + 4x v_cvt_pk_bf16_f32 per A-frag (RNE rounding).
// Cb16[m*256+n] = bf16(acc + bias[n]).
template <int KT>
__device__ __forceinline__ void gemm_glds32A(char* lds,
                                             const float* __restrict__ Af,
                                             const unsigned short* __restrict__ Bw,
                                             const float* __restrict__ bias,
                                             unsigned short* __restrict__ Ch,
                                             int M, int bid, int nwg) {
    constexpr int K = KT * 64;
    int tid = threadIdx.x;
    int wid = tid >> 6, lane = tid & 63;

    int qd = nwg >> 3, r = nwg & 7;
    int xcd = bid & 7, seq = bid >> 3;
    int wgid = (xcd < r) ? (xcd * (qd + 1) + seq) : (r * (qd + 1) + (xcd - r) * qd + seq);
    int mt = wgid >> 2;
    int nt = wgid & 3;
    int m0 = mt * 64, n0 = nt * 64;

    int lr = lane & 15, lq = lane >> 4;

    f32x4 acc[4];
#pragma unroll
    for (int j = 0; j < 4; ++j) acc[j] = (f32x4)(0.f);

#define STAGE(BI, KTI) do {                                                           \
    char* bufA = lds + (BI) * 24576;                                                  \
    char* bufB = bufA + 16384;                                                        \
    _Pragma("unroll")                                                                 \
    for (int i_ = 0; i_ < 4; ++i_) {                                                  \
        int L_ = tid + (i_ << 8);                                                     \
        int row_ = L_ >> 4, ch_ = L_ & 15;                                            \
        int gr_ = m0 + row_; gr_ = gr_ < M ? gr_ : M - 1;                             \
        glds16((const char*)Af + (size_t)gr_ * (K * 4) + ((KTI) << 8) + ((ch_ ^ (row_ & 7)) << 4), \
               bufA + (L_ << 4));                                                     \
    }                                                                                 \
    _Pragma("unroll")                                                                 \
    for (int i_ = 0; i_ < 2; ++i_) {                                                  \
        int L_ = tid + (i_ << 8);                                                     \
        int row_ = L_ >> 3, c_ = L_ & 7;                                              \
        glds16((const char*)Bw + (size_t)(n0 + row_) * (K * 2) + ((KTI) << 7) + ((c_ ^ (row_ & 7)) << 4), \
               bufB + (L_ << 4));                                                     \
    }                                                                                 \
} while (0)

#define GMFMA(BI) do {                                                                \
    char* bufA = lds + (BI) * 24576;                                                  \
    char* bufB = bufA + 16384;                                                        \
    _Pragma("unroll")                                                                 \
    for (int s_ = 0; s_ < 2; ++s_) {                                                  \
        int cg_ = (s_ << 2) + lq;                                                     \
        int arow_ = (wid << 4) + lr;                                                  \
        f32x4 a0_ = *(f32x4*)(bufA + arow_ * 256 + ((((cg_ << 1))     ^ (arow_ & 7)) << 4)); \
        f32x4 a1_ = *(f32x4*)(bufA + arow_ * 256 + ((((cg_ << 1) | 1) ^ (arow_ & 7)) << 4)); \
        unsigned w0_, w1_, w2_, w3_;                                                  \
        asm("v_cvt_pk_bf16_f32 %0, %1, %2" : "=v"(w0_) : "v"(a0_[0]), "v"(a0_[1]));   \
        asm("v_cvt_pk_bf16_f32 %0, %1, %2" : "=v"(w1_) : "v"(a0_[2]), "v"(a0_[3]));   \
        asm("v_cvt_pk_bf16_f32 %0, %1, %2" : "=v"(w2_) : "v"(a1_[0]), "v"(a1_[1]));   \
        asm("v_cvt_pk_bf16_f32 %0, %1, %2" : "=v"(w3_) : "v"(a1_[2]), "v"(a1_[3]));   \
        bf16x8 af_ = __builtin_bit_cast(bf16x8, make_uint4(w0_, w1_, w2_, w3_));      \
        _Pragma("unroll")                                                             \
        for (int j_ = 0; j_ < 4; ++j_) {                                              \
            int brow_ = (j_ << 4) + lr;                                               \
            bf16x8 bf_ = *(bf16x8*)(bufB + brow_ * 128 + ((cg_ ^ (brow_ & 7)) << 4)); \
            acc[j_] = __builtin_amdgcn_mfma_f32_16x16x32_bf16(af_, bf_, acc[j_], 0, 0, 0); \
        }                                                                             \
    }                                                                                 \
} while (0)

    STAGE(0, 0);
    if (KT > 1) STAGE(1, 1);
#pragma unroll
    for (int kt = 0; kt < KT; ++kt) {
        if (kt + 1 < KT) {
            asm volatile("s_waitcnt vmcnt(6)" ::: "memory");   // kt's 6 landed; kt+1's 6 in flight
        } else {
            asm volatile("s_waitcnt vmcnt(0)" ::: "memory");
        }
        __builtin_amdgcn_s_barrier();                          // kt's tile visible block-wide
        __builtin_amdgcn_sched_barrier(0);
        GMFMA(kt & 1);
        __builtin_amdgcn_sched_barrier(0);
        __builtin_amdgcn_s_barrier();                          // all waves done reading buf kt
        if (kt + 2 < KT) STAGE(kt & 1, kt + 2);                // refill the just-freed buffer
    }

    int mb = m0 + (wid << 4) + (lq << 2);
#pragma unroll
    for (int j = 0; j < 4; ++j) {
        int n = n0 + (j << 4) + lr;
        float bn = bias[n];
#pragma unroll
        for (int e = 0; e < 4; ++e) {
            int m = mb + e;
            if (m < M) Ch[(size_t)m * 256 + n] = (unsigned short)f2bf(acc[j][e] + bn);
        }
    }
#undef STAGE
#undef GMFMA
}

// ======== glds GEMM (bf16 A): 64x64, 3-buffer counted vmcnt(4) — out path ========
template <int MODE, int KT>
__device__ __forceinline__ void gemm_glds(char* lds,
                                          const unsigned short* __restrict__ Ah,
                                          const unsigned short* __restrict__ Bw,
                                          const float* __restrict__ bias,
                                          const float* __restrict__ resid,
                                          const float* __restrict__ wview,
                                          void* __restrict__ Cptr,
                                          int M, int nt_shift, int bid, int nwg) {
    constexpr int K = KT * 64;
    int tid = threadIdx.x;
    int wid = tid >> 6, lane = tid & 63;

    int qd = nwg >> 3, r = nwg & 7;
    int xcd = bid & 7, seq = bid >> 3;
    int wgid = (xcd < r) ? (xcd * (qd + 1) + seq) : (r * (qd + 1) + (xcd - r) * qd + seq);
    int mt = wgid >> nt_shift;
    int nt = wgid & ((1 << nt_shift) - 1);
    int m0 = mt * 64, n0 = nt * 64;

    int lr = lane & 15, lq = lane >> 4;
    float* Cf = (float*)Cptr;

    f32x4 acc[4];
#pragma unroll
    for (int j = 0; j < 4; ++j) acc[j] = (f32x4)(0.f);

#define STAGE(BI, KTI) do {                                                           \
    char* buf = lds + (BI) * 16384;                                                   \
    int k0b = (KTI) << 7;                                                             \
    _Pragma("unroll")                                                                 \
    for (int i_ = 0; i_ < 2; ++i_) {                                                  \
        int L_ = tid + (i_ << 8);                                                     \
        int row_ = L_ >> 3, c_ = L_ & 7;                                              \
        glds16((const char*)Ah + (size_t)(m0 + row_) * (K * 2) + k0b + ((c_ ^ (row_ & 7)) << 4), \
               buf + (L_ << 4));                                                      \
    }                                                                                 \
    _Pragma("unroll")                                                                 \
    for (int i_ = 0; i_ < 2; ++i_) {                                                  \
        int L_ = tid + (i_ << 8);                                                     \
        int row_ = L_ >> 3, c_ = L_ & 7;                                              \
        glds16((const char*)Bw + (size_t)(n0 + row_) * (K * 2) + k0b + ((c_ ^ (row_ & 7)) << 4), \
               buf + 8192 + (L_ << 4));                                               \
    }                                                                                 \
} while (0)

#define GMFMA(BI) do {                                                                \
    char* Abb = lds + (BI) * 16384;                                                   \
    char* Bbb = Abb + 8192;                                                           \
    _Pragma("unroll")                                                                 \
    for (int s_ = 0; s_ < 2; ++s_) {                                                  \
        int chunk_ = (s_ << 2) + lq;                                                  \
        int arow_ = (wid << 4) + lr;                                                  \
        bf16x8 af_ = *(bf16x8*)(Abb + arow_ * 128 + ((chunk_ ^ (arow_ & 7)) << 4));   \
        _Pragma("unroll")                                                             \
        for (int j_ = 0; j_ < 4; ++j_) {                                              \
            int brow_ = (j_ << 4) + lr;                                               \
            bf16x8 bf_ = *(bf16x8*)(Bbb + brow_ * 128 + ((chunk_ ^ (brow_ & 7)) << 4)); \
            acc[j_] = __builtin_amdgcn_mfma_f32_16x16x32_bf16(af_, bf_, acc[j_], 0, 0, 0); \
        }                                                                             \
    }                                                                                 \
} while (0)

    STAGE(0, 0);
    if (KT > 1) STAGE(1, 1);
#pragma unroll
    for (int kt = 0; kt < KT; ++kt) {
        if (kt + 1 < KT) {
            asm volatile("s_waitcnt vmcnt(4)" ::: "memory");
        } else {
            asm volatile("s_waitcnt vmcnt(0)" ::: "memory");
        }
        __builtin_amdgcn_s_barrier();
        __builtin_amdgcn_sched_barrier(0);
        if (kt + 2 < KT) STAGE((kt + 2) % 3, kt + 2);
        GMFMA(kt % 3);
        __builtin_amdgcn_sched_barrier(0);
    }

    {
        float s = 0.f;
#pragma unroll
        for (int v = 0; v < 6; ++v) {
            float x = wview[v];
            s += (x > 20.f) ? x : log1pf(expf(x));
        }
        float f = s / fmaxf(s, 1e-6f);
        int mb = m0 + (wid << 4) + (lq << 2);
#pragma unroll
        for (int j = 0; j < 4; ++j) {
            int n = n0 + (j << 4) + lr;
            float bn = bias[n];
            if (mb + 4 <= M) {
                float4 o;
                float* oo = (float*)&o;
#pragma unroll
                for (int e = 0; e < 4; ++e)
                    oo[e] = acc[j][e] + f * (bn + resid[(size_t)(mb + e) * 256 + n]);
                *(float4*)(Cf + (size_t)n * M + mb) = o;
            } else {
#pragma unroll
                for (int e = 0; e < 4; ++e) {
                    int m = mb + e;
                    if (m < M) Cf[(size_t)n * M + m] = acc[j][e] + f * (bn + resid[(size_t)m * 256 + n]);
                }
            }
        }
    }
#undef STAGE
#undef GMFMA
}

// ---------------- qout GEMM body: fp32 A reg-staged (64x64, 2-stage) ----------------
template <int KT>
__device__ __forceinline__ void gemm_f32A(char* base0, char* base1,
                                          const float* __restrict__ Af,
                                          const unsigned short* __restrict__ Bw,
                                          const float* __restrict__ bias,
                                          float* __restrict__ Cf,
                                          int M, int nt_shift, int bid, int nwg) {
    constexpr int K = KT * 64;
    int tid = threadIdx.x;
    int wid = tid >> 6, lane = tid & 63;

    int qd = nwg >> 3, r = nwg & 7;
    int xcd = bid & 7, seq = bid >> 3;
    int wgid = (xcd < r) ? (xcd * (qd + 1) + seq) : (r * (qd + 1) + (xcd - r) * qd + seq);
    int mt = wgid >> nt_shift;
    int nt = wgid & ((1 << nt_shift) - 1);
    int m0 = mt * 64, n0 = nt * 64;

    int lr = lane & 15, lq = lane >> 4;
    int arow_s = tid >> 4;
    int ac4 = tid & 15;

    f32x4 acc[4];
#pragma unroll
    for (int j = 0; j < 4; ++j) acc[j] = (f32x4)(0.f);

    float4 aF[2][4];
    uint4  bR[2][2];
    const float4 zf4 = make_float4(0.f, 0.f, 0.f, 0.f);

#define QLOADG(S, KTI) do {                                                           \
    int k0 = (KTI) << 6;                                                              \
    _Pragma("unroll")                                                                 \
    for (int p_ = 0; p_ < 4; ++p_) {                                                  \
        int row_ = p_ * 16 + arow_s;                                                  \
        bool av_ = (m0 + row_) < M;                                                   \
        aF[S][p_] = av_ ? *(const float4*)(Af + (size_t)(m0 + row_) * K + k0 + ac4 * 4) : zf4; \
    }                                                                                 \
    _Pragma("unroll")                                                                 \
    for (int i_ = 0; i_ < 2; ++i_) {                                                  \
        int s_ = tid + (i_ << 8);                                                     \
        int row_ = s_ >> 3, c_ = s_ & 7;                                              \
        bR[S][i_] = *(const uint4*)(Bw + (size_t)(n0 + row_) * K + k0 + c_ * 8);      \
    }                                                                                 \
} while (0)

#define QTOLDS(S, PB) do {                                                            \
    char* Abb = (PB) ? base1 : base0;                                                 \
    _Pragma("unroll")                                                                 \
    for (int p_ = 0; p_ < 4; ++p_) {                                                  \
        int row_ = p_ * 16 + arow_s;                                                  \
        const float* f_ = (const float*)&aF[S][p_];                                   \
        uint2 w_;                                                                     \
        w_.x = f2bf(f_[0]) | (f2bf(f_[1]) << 16);                                     \
        w_.y = f2bf(f_[2]) | (f2bf(f_[3]) << 16);                                     \
        int byte_ = row_ * 128 + (((ac4 >> 1) ^ (row_ & 7)) << 4) + ((ac4 & 1) << 3); \
        *(uint2*)(Abb + byte_) = w_;                                                  \
    }                                                                                 \
    char* Bbb = Abb + 8192;                                                           \
    _Pragma("unroll")                                                                 \
    for (int i_ = 0; i_ < 2; ++i_) {                                                  \
        int s_ = tid + (i_ << 8);                                                     \
        int row_ = s_ >> 3, c_ = s_ & 7;                                              \
        *(uint4*)(Bbb + row_ * 128 + ((c_ ^ (row_ & 7)) << 4)) = bR[S][i_];           \
    }                                                                                 \
} while (0)

#define QMFMAS(PB) do {                                                               \
    char* Abb = (PB) ? base1 : base0;                                                 \
    char* Bbb = Abb + 8192;                                                           \
    _Pragma("unroll")                                                                 \
    for (int s_ = 0; s_ < 2; ++s_) {                                                  \
        int chunk_ = (s_ << 2) + lq;                                                  \
        int arow_ = (wid << 4) + lr;                                                  \
        bf16x8 af_ = *(bf16x8*)(Abb + arow_ * 128 + ((chunk_ ^ (arow_ & 7)) << 4));   \
        _Pragma("unroll")                                                             \
        for (int j_ = 0; j_ < 4; ++j_) {                                              \
            int brow_ = (j_ << 4) + lr;                                               \
            bf16x8 bf_ = *(bf16x8*)(Bbb + brow_ * 128 + ((chunk_ ^ (brow_ & 7)) << 4)); \
            acc[j_] = __builtin_amdgcn_mfma_f32_16x16x32_bf16(af_, bf_, acc[j_], 0, 0, 0); \
        }                                                                             \
    }                                                                                 \
} while (0)

    QLOADG(0, 0);
#pragma unroll
    for (int kt = 0; kt < KT; ++kt) {
        if (kt + 1 < KT) QLOADG((kt + 1) & 1, kt + 1);
        QTOLDS(kt & 1, kt & 1);
        __builtin_amdgcn_sched_barrier(0);
        asm volatile("s_waitcnt lgkmcnt(0)" ::: "memory");
        __builtin_amdgcn_s_barrier();
        __builtin_amdgcn_sched_barrier(0);
        QMFMAS(kt & 1);
    }

    int mb = m0 + (wid << 4) + (lq << 2);
#pragma unroll
    for (int j = 0; j < 4; ++j) {
        int n = n0 + (j << 4) + lr;
        if (n >= 96) continue;
        float bn = bias[n];
#pragma unroll
        for (int e = 0; e < 4; ++e) {
            int m = mb + e;
            if (m < M) Cf[(size_t)m * 96 + n] = acc[j][e] + bn;
        }
    }
#undef QLOADG
#undef QTOLDS
#undef QMFMAS
}

// val (916 blocks, fp32-A glds) + qout (314 blocks, reg-staged) in one launch
__global__ __launch_bounds__(256, 3) void dual_gemm(const float* __restrict__ lt,
                                                    const unsigned short* __restrict__ W2b,
                                                    const float* __restrict__ vpb,
                                                    unsigned short* __restrict__ valB,
                                                    const float* __restrict__ bqq,
                                                    const unsigned short* __restrict__ WQb,
                                                    const float* __restrict__ bqp,
                                                    float* __restrict__ qout) {
    __shared__ char lds[49152];
    if (blockIdx.x < 916)
        gemm_glds32A<12>(lds, lt, W2b, vpb, valB, 14652, blockIdx.x, 916);
    else
        gemm_f32A<4>(lds, lds + 16384, bqq, WQb, bqp, qout, Q_TOT, 1, blockIdx.x - 916, 314);
}

__global__ __launch_bounds__(256, 3) void out_gemm(const unsigned short* __restrict__ sampavgB,
                                                   const unsigned short* __restrict__ opwb,
                                                   const float* __restrict__ opb,
                                                   const float* __restrict__ bqq,
                                                   const float* __restrict__ wview,
                                                   float* __restrict__ out) {
    __shared__ char lds[49152];
    gemm_glds<1, 4>(lds, sampavgB, opwb, opb, bqq, wview,
                    (void*)out, Q_TOT, 2, blockIdx.x, gridDim.x);
}

// ---------------- deformable sampling: bf16 table, dwordx2 gathers ----------------
__global__ __launch_bounds__(256) void sample_kernel(const unsigned short* __restrict__ valB,
                                                     const float* __restrict__ ref2d,
                                                     const float* __restrict__ qout,
                                                     const float* __restrict__ vwn,
                                                     unsigned short* __restrict__ sampavgB) {
    __shared__ uint4  sOff[4 * 240];
    __shared__ float4 sW[4 * 240];
    __shared__ float4 sAt[4 * 8];
    __shared__ float  sVw[8];
    int tid = threadIdx.x;
    int qb = blockIdx.x * 4;

    if (tid < 32) {
        int ql = tid >> 3, h = tid & 7;
        const float* qo = qout + (size_t)(qb + ql) * 96 + 64 + h * 4;
        float a0 = qo[0], a1 = qo[1], a2 = qo[2], a3 = qo[3];
        float mx = fmaxf(fmaxf(a0, a1), fmaxf(a2, a3));
        float e0 = __expf(a0 - mx), e1 = __expf(a1 - mx), e2 = __expf(a2 - mx), e3 = __expf(a3 - mx);
        float inv = 1.0f / (e0 + e1 + e2 + e3);
        sAt[ql * 8 + h] = make_float4(e0 * inv, e1 * inv, e2 * inv, e3 * inv);
        if (tid < 8) sVw[tid] = vwn[tid < 6 ? tid : 0];
    }
    __syncthreads();

#pragma unroll
    for (int t = tid; t < 768; t += 256) {
        int ql = t / 192;
        int rem = t - ql * 192;
        int v = rem >> 5;
        int h = (rem >> 2) & 7;
        int p = rem & 3;
        int q = qb + ql;
        const float* qo = qout + (size_t)q * 96;
        float ox = qo[h * 8 + 2 * p];
        float oy = qo[h * 8 + 2 * p + 1];
        float at = ((const float*)&sAt[ql * 8 + h])[p];
        float scale = at * sVw[v];

        float rx = ref2d[(size_t)(v * Q_TOT + q) * 2 + 0];
        float ry = ref2d[(size_t)(v * Q_TOT + q) * 2 + 1];
        float x = rx * 66.0f + ox - 0.5f;
        float y = ry * 37.0f + oy - 0.5f;
        float xf = floorf(x), yf = floorf(y);
        float fx = x - xf, fy = y - yf;
        int xi = (int)xf, yi = (int)yf;

        float cw[4] = { (1.f - fx) * (1.f - fy), fx * (1.f - fy), (1.f - fx) * fy, fx * fy };
        unsigned off[4];
#pragma unroll
        for (int cyi = 0; cyi < 2; ++cyi) {
#pragma unroll
            for (int cxi = 0; cxi < 2; ++cxi) {
                int cx = xi + cxi, cy = yi + cyi;
                bool ok = (cx >= 0) && (cx < WP_) && (cy >= 0) && (cy < HP_);
                int ccx = cx < 0 ? 0 : (cx > WP_ - 1 ? WP_ - 1 : cx);
                int ccy = cy < 0 ? 0 : (cy > HP_ - 1 ? HP_ - 1 : cy);
                int c_ = cyi * 2 + cxi;
                off[c_] = (unsigned)((v * NTOK + ccy * WP_ + ccx) << 9);
                cw[c_] = ok ? cw[c_] * scale : 0.f;
            }
        }
        int slot = ql * 240 + v * 40 + h * 5 + p;
        sOff[slot] = make_uint4(off[0], off[1], off[2], off[3]);
        sW[slot]   = make_float4(cw[0], cw[1], cw[2], cw[3]);
    }
    __syncthreads();

    int ql = tid >> 6;
    int lane = tid & 63;
    int h = lane >> 3, d4 = (lane & 7) << 2;
    unsigned coff = (unsigned)((h * 32 + d4) << 1);
    const char* vbase = (const char*)valB;
    float acc0 = 0.f, acc1 = 0.f, acc2 = 0.f, acc3 = 0.f;
#pragma unroll
    for (int v = 0; v < NVIEW; ++v) {
#pragma unroll
        for (int p = 0; p < 4; ++p) {
            int slot = ql * 240 + v * 40 + h * 5 + p;
            uint4 off = sOff[slot];
            float4 w = sW[slot];
            uint2 r0 = *(const uint2*)(vbase + (off.x + coff));
            uint2 r1 = *(const uint2*)(vbase + (off.y + coff));
            uint2 r2 = *(const uint2*)(vbase + (off.z + coff));
            uint2 r3 = *(const uint2*)(vbase + (off.w + coff));
            float g0, g1;
            g0 = __builtin_bit_cast(float, r0.x << 16); g1 = __builtin_bit_cast(float, r0.x & 0xFFFF0000u);
            acc0 += w.x * g0; acc1 += w.x * g1;
            g0 = __builtin_bit_cast(float, r0.y << 16); g1 = __builtin_bit_cast(float, r0.y & 0xFFFF0000u);
            acc2 += w.x * g0; acc3 += w.x * g1;
            g0 = __builtin_bit_cast(float, r1.x << 16); g1 = __builtin_bit_cast(float, r1.x & 0xFFFF0000u);
            acc0 += w.y * g0; acc1 += w.y * g1;
            g0 = __builtin_bit_cast(float, r1.y << 16); g1 = __builtin_bit_cast(float, r1.y & 0xFFFF0000u);
            acc2 += w.y * g0; acc3 += w.y * g1;
            g0 = __builtin_bit_cast(float, r2.x << 16); g1 = __builtin_bit_cast(float, r2.x & 0xFFFF0000u);
            acc0 += w.z * g0; acc1 += w.z * g1;
            g0 = __builtin_bit_cast(float, r2.y << 16); g1 = __builtin_bit_cast(float, r2.y & 0xFFFF0000u);
            acc2 += w.z * g0; acc3 += w.z * g1;
            g0 = __builtin_bit_cast(float, r3.x << 16); g1 = __builtin_bit_cast(float, r3.x & 0xFFFF0000u);
            acc0 += w.w * g0; acc1 += w.w * g1;
            g0 = __builtin_bit_cast(float, r3.y << 16); g1 = __builtin_bit_cast(float, r3.y & 0xFFFF0000u);
            acc2 += w.w * g0; acc3 += w.w * g1;
        }
    }
    int q = qb + ql;
    unsigned u0 = f2bf(acc0) | (f2bf(acc1) << 16);
    unsigned u1 = f2bf(acc2) | (f2bf(acc3) << 16);
    *(uint2*)(sampavgB + (size_t)q * CC_ + h * 32 + d4) = make_uint2(u0, u1);
}

extern "C" void kernel_launch(void* const* d_in, const int* in_sizes, int n_in,
                              void* d_out, int out_size, void* d_ws, size_t ws_size,
                              hipStream_t stream) {
    const float* lt   = (const float*)d_in[0];
    const float* l2i  = (const float*)d_in[1];
    const float* proj = (const float*)d_in[2];
    const float* bqq  = (const float*)d_in[3];
    const float* wv   = (const float*)d_in[4];
    const float* vpw  = (const float*)d_in[5];
    const float* vpb  = (const float*)d_in[6];
    const float* sow  = (const float*)d_in[7];
    const float* sob  = (const float*)d_in[8];
    const float* aww  = (const float*)d_in[9];
    const float* awb  = (const float*)d_in[10];
    const float* opw  = (const float*)d_in[11];
    const float* opb  = (const float*)d_in[12];
    float* out = (float*)d_out;

    char* ws = (char*)d_ws;
    unsigned short* W2b   = (unsigned short*)(ws);             // 393216
    unsigned short* opwb  = (unsigned short*)(ws + 393216);    // 131072
    unsigned short* WQb   = (unsigned short*)(ws + 524288);    // 65536
    float*          bqp   = (float*)(ws + 589824);             // 512
    float*          vwn   = (float*)(ws + 590336);             // 512
    float*          ref2d = (float*)(ws + 590848);             // 480000
    float*          qout  = (float*)(ws + 1070848);            // 3840000 -> ends 4910848
    unsigned short* valB  = (unsigned short*)(ws + 4910848);   // 7501824 -> ends 12412672
    unsigned short* sampavgB = (unsigned short*)(ws + 12412672); // 5120000 -> ends 17532672

    hipLaunchKernelGGL(prep_all, dim3(779), dim3(256), 0, stream,
                       vpw, proj, opw, l2i, sow, sob, aww, awb, wv,
                       W2b, opwb, ref2d, WQb, bqp, vwn);
    hipLaunchKernelGGL(dual_gemm, dim3(1230), dim3(256), 0, stream,
                       lt, W2b, vpb, valB, bqq, WQb, bqp, qout);
    hipLaunchKernelGGL(sample_kernel, dim3(Q_TOT / 4), dim3(256), 0, stream,
                       valB, ref2d, qout, vwn, sampavgB);
    hipLaunchKernelGGL(out_gemm, dim3(628), dim3(256), 0, stream,
                       sampavgB, opwb, opb, bqq, wv, out);
}

// Round 21
// 78.798 us; speedup vs baseline: 1.0638x; 1.0523x over previous
//
#include <hip/hip_runtime.h>
#include <math.h>

#define Q_TOT 10000
#define NVIEW 6
#define NTOK  2442
#define HP_   37
#define WP_   66
#define CD_   768
#define CC_   256

typedef __attribute__((ext_vector_type(8))) short bf16x8;
typedef __attribute__((ext_vector_type(4))) float f32x4;

__device__ inline unsigned f2bf(float f) {
    unsigned u = __builtin_bit_cast(unsigned, f);
    unsigned r = u + 0x7FFFu + ((u >> 16) & 1u);
    return r >> 16;
}

__device__ __forceinline__ void glds16(const void* g, void* l) {
    __builtin_amdgcn_global_load_lds(
        (const __attribute__((address_space(1))) unsigned int*)g,
        (__attribute__((address_space(3))) unsigned int*)l,
        16, 0, 0);
}

// ---------------- fused prep: w2 (768 blocks) + opw-cvt/ref2d/concat (395 blocks) -----
__global__ __launch_bounds__(256) void prep_all(const float* __restrict__ vp_w,
                                                const float* __restrict__ proj_w,
                                                const float* __restrict__ opw,
                                                const float* __restrict__ l2i,
                                                const float* __restrict__ so_w,
                                                const float* __restrict__ so_b,
                                                const float* __restrict__ aw_w,
                                                const float* __restrict__ aw_b,
                                                const float* __restrict__ wview,
                                                unsigned short* __restrict__ W2b,
                                                unsigned short* __restrict__ opwb,
                                                float* __restrict__ ref2d,
                                                unsigned short* __restrict__ WQb,
                                                float* __restrict__ bqp,
                                                float* __restrict__ vwn) {
    int b0 = blockIdx.x, tid = threadIdx.x;
    if (b0 < 768) {
        int o2 = b0 / 3;
        int c = (b0 % 3) * 256 + tid;
        __shared__ float vps[256];
        vps[tid] = vp_w[(size_t)o2 * 256 + tid];
        __syncthreads();
        float acc = 0.f;
#pragma unroll 16
        for (int o = 0; o < 256; ++o) {
            acc += vps[o] * proj_w[(size_t)o * CD_ + c];
        }
        W2b[(size_t)o2 * CD_ + c] = (unsigned short)f2bf(acc);
        return;
    }
    int b = b0 - 768;
    if (b < 32) {
        int i = b * 256 + tid;                 // < 8192
        float4 a = *(const float4*)(opw + (size_t)i * 8);
        float4 c4 = *(const float4*)(opw + (size_t)i * 8 + 4);
        uint4 o;
        o.x = f2bf(a.x) | (f2bf(a.y) << 16);
        o.y = f2bf(a.z) | (f2bf(a.w) << 16);
        o.z = f2bf(c4.x) | (f2bf(c4.y) << 16);
        o.w = f2bf(c4.z) | (f2bf(c4.w) << 16);
        *(uint4*)(opwb + (size_t)i * 8) = o;
    } else if (b < 267) {
        int idx = (b - 32) * 256 + tid;
        if (idx < NVIEW * Q_TOT) {
            int v = idx / Q_TOT, q = idx % Q_TOT;
            int wq = q % 100, hq = q / 100;
            float wx = (wq + 0.5f) * 1.024f - 51.2f;
            float wy = (hq + 0.5f) * 1.024f - 51.2f;
            const float* L = l2i + v * 16;
            float L0=L[0],L1=L[1],L2=L[2],L3=L[3],L4=L[4],L5=L[5],L6=L[6],L7=L[7];
            float L8=L[8],L9=L[9],L10=L[10],L11=L[11];
            float sw = 0.f, sx = 0.f, sy = 0.f;
#pragma unroll
            for (int d = 0; d < 4; ++d) {
                float zs = (0.5f + (float)d * (7.0f / 3.0f)) * 0.125f;
                float wz = zs * 8.0f - 5.0f;
                float c0 = L0 * wx + L1 * wy + L2 * wz + L3;
                float c1 = L4 * wx + L5 * wy + L6 * wz + L7;
                float c2 = L8 * wx + L9 * wy + L10 * wz + L11;
                bool bm = c2 > 1e-5f;
                float dc = fmaxf(c2, 1e-5f);
                float u  = (c0 / dc) * 0.5775f;
                float vv = (c1 / dc) * 0.5775f;
                bool in_img = (u >= 0.f) && (u <= 923.f) && (vv >= 0.f) && (vv <= 517.f);
                bool valid = bm && in_img;
                float refx = fminf(fmaxf(u / 923.0f, 0.f), 1.f);
                float refy = fminf(fmaxf(vv / 517.0f, 0.f), 1.f);
                float w = valid ? 1.0f : 1e-6f;
                sw += w; sx += refx * w; sy += refy * w;
            }
            float den = fmaxf(sw, 1e-6f);
            ref2d[(size_t)idx * 2 + 0] = sx / den;
            ref2d[(size_t)idx * 2 + 1] = sy / den;
        }
    } else {
        int row = b - 267, col = tid;
        float v = (row < 64) ? so_w[row * 256 + col] : (row < 96 ? aw_w[(row - 64) * 256 + col] : 0.f);
        WQb[row * 256 + col] = (unsigned short)f2bf(v);
        if (row == 0 && col < 128) bqp[col] = (col < 64) ? so_b[col] : (col < 96 ? aw_b[col - 64] : 0.f);
        if (row == 1 && col == 0) {
            float sp[6], swv = 0.f;
#pragma unroll
            for (int vv = 0; vv < NVIEW; ++vv) {
                float x = wview[vv];
                float s = (x > 20.f) ? x : log1pf(expf(x));
                sp[vv] = s; swv += s;
            }
            float inv = 1.0f / fmaxf(swv, 1e-6f);
#pragma unroll
            for (int vv = 0; vv < NVIEW; ++vv) vwn[vv] = sp[vv] * inv;
            vwn[6] = swv * inv;
            vwn[7] = 0.f;
        }
    }
}

// ======== val GEMM: fp32-A glds, 64x64 tile, 2 buffers, counted vmcnt(6) ========
// Per buffer: A fp32 16KB [64 rows x 16 chunks, chunk^=(row&7)] + B bf16 8KB.
// Consume: 2x ds_read_b128 fp32 + 4x v_cvt_pk_bf16_f32 per A-frag (RNE rounding).
// Cb16[m*256+n] = bf16(acc + bias[n]).
template <int KT>
__device__ __forceinline__ void gemm_glds32A(char* lds,
                                             const float* __restrict__ Af,
                                             const unsigned short* __restrict__ Bw,
                                             const float* __restrict__ bias,
                                             unsigned short* __restrict__ Ch,
                                             int M, int bid, int nwg) {
    constexpr int K = KT * 64;
    int tid = threadIdx.x;
    int wid = tid >> 6, lane = tid & 63;

    int qd = nwg >> 3, r = nwg & 7;
    int xcd = bid & 7, seq = bid >> 3;
    int wgid = (xcd < r) ? (xcd * (qd + 1) + seq) : (r * (qd + 1) + (xcd - r) * qd + seq);
    int mt = wgid >> 2;
    int nt = wgid & 3;
    int m0 = mt * 64, n0 = nt * 64;

    int lr = lane & 15, lq = lane >> 4;

    f32x4 acc[4];
#pragma unroll
    for (int j = 0; j < 4; ++j) acc[j] = (f32x4)(0.f);

#define STAGE(BI, KTI) do {                                                           \
    char* bufA = lds + (BI) * 24576;                                                  \
    char* bufB = bufA + 16384;                                                        \
    _Pragma("unroll")                                                                 \
    for (int i_ = 0; i_ < 4; ++i_) {                                                  \
        int L_ = tid + (i_ << 8);                                                     \
        int row_ = L_ >> 4, ch_ = L_ & 15;                                            \
        int gr_ = m0 + row_; gr_ = gr_ < M ? gr_ : M - 1;                             \
        glds16((const char*)Af + (size_t)gr_ * (K * 4) + ((KTI) << 8) + ((ch_ ^ (row_ & 7)) << 4), \
               bufA + (L_ << 4));                                                     \
    }                                                                                 \
    _Pragma("unroll")                                                                 \
    for (int i_ = 0; i_ < 2; ++i_) {                                                  \
        int L_ = tid + (i_ << 8);                                                     \
        int row_ = L_ >> 3, c_ = L_ & 7;                                              \
        glds16((const char*)Bw + (size_t)(n0 + row_) * (K * 2) + ((KTI) << 7) + ((c_ ^ (row_ & 7)) << 4), \
               bufB + (L_ << 4));                                                     \
    }                                                                                 \
} while (0)

#define GMFMA(BI) do {                                                                \
    char* bufA = lds + (BI) * 24576;                                                  \
    char* bufB = bufA + 16384;                                                        \
    _Pragma("unroll")                                                                 \
    for (int s_ = 0; s_ < 2; ++s_) {                                                  \
        int cg_ = (s_ << 2) + lq;                                                     \
        int arow_ = (wid << 4) + lr;                                                  \
        f32x4 a0_ = *(f32x4*)(bufA + arow_ * 256 + ((((cg_ << 1))     ^ (arow_ & 7)) << 4)); \
        f32x4 a1_ = *(f32x4*)(bufA + arow_ * 256 + ((((cg_ << 1) | 1) ^ (arow_ & 7)) << 4)); \
        unsigned w0_, w1_, w2_, w3_;                                                  \
        asm("v_cvt_pk_bf16_f32 %0, %1, %2" : "=v"(w0_) : "v"(a0_[0]), "v"(a0_[1]));   \
        asm("v_cvt_pk_bf16_f32 %0, %1, %2" : "=v"(w1_) : "v"(a0_[2]), "v"(a0_[3]));   \
        asm("v_cvt_pk_bf16_f32 %0, %1, %2" : "=v"(w2_) : "v"(a1_[0]), "v"(a1_[1]));   \
        asm("v_cvt_pk_bf16_f32 %0, %1, %2" : "=v"(w3_) : "v"(a1_[2]), "v"(a1_[3]));   \
        bf16x8 af_ = __builtin_bit_cast(bf16x8, make_uint4(w0_, w1_, w2_, w3_));      \
        _Pragma("unroll")                                                             \
        for (int j_ = 0; j_ < 4; ++j_) {                                              \
            int brow_ = (j_ << 4) + lr;                                               \
            bf16x8 bf_ = *(bf16x8*)(bufB + brow_ * 128 + ((cg_ ^ (brow_ & 7)) << 4)); \
            acc[j_] = __builtin_amdgcn_mfma_f32_16x16x32_bf16(af_, bf_, acc[j_], 0, 0, 0); \
        }                                                                             \
    }                                                                                 \
} while (0)

    STAGE(0, 0);
    if (KT > 1) STAGE(1, 1);
#pragma unroll
    for (int kt = 0; kt < KT; ++kt) {
        if (kt + 1 < KT) {
            asm volatile("s_waitcnt vmcnt(6)" ::: "memory");   // kt's 6 landed; kt+1's 6 in flight
        } else {
            asm volatile("s_waitcnt vmcnt(0)" ::: "memory");
        }
        __builtin_amdgcn_s_barrier();                          // kt's tile visible block-wide
        __builtin_amdgcn_sched_barrier(0);
        GMFMA(kt & 1);
        __builtin_amdgcn_sched_barrier(0);
        __builtin_amdgcn_s_barrier();                          // all waves done reading buf kt
        if (kt + 2 < KT) STAGE(kt & 1, kt + 2);                // refill the just-freed buffer
    }

    int mb = m0 + (wid << 4) + (lq << 2);
#pragma unroll
    for (int j = 0; j < 4; ++j) {
        int n = n0 + (j << 4) + lr;
        float bn = bias[n];
#pragma unroll
        for (int e = 0; e < 4; ++e) {
            int m = mb + e;
            if (m < M) Ch[(size_t)m * 256 + n] = (unsigned short)f2bf(acc[j][e] + bn);
        }
    }
#undef STAGE
#undef GMFMA
}

// ======== glds GEMM (bf16 A): 64x64, 3-buffer counted vmcnt(4) — out path ========
template <int MODE, int KT>
__device__ __forceinline__ void gemm_glds(char* lds,
                                          const unsigned short* __restrict__ Ah,
                                          const unsigned short* __restrict__ Bw,
                                          const float* __restrict__ bias,
                                          const float* __restrict__ resid,
                                          const float* __restrict__ wview,
                                          void* __restrict__ Cptr,
                                          int M, int nt_shift, int bid, int nwg) {
    constexpr int K = KT * 64;
    int tid = threadIdx.x;
    int wid = tid >> 6, lane = tid & 63;

    int qd = nwg >> 3, r = nwg & 7;
    int xcd = bid & 7, seq = bid >> 3;
    int wgid = (xcd < r) ? (xcd * (qd + 1) + seq) : (r * (qd + 1) + (xcd - r) * qd + seq);
    int mt = wgid >> nt_shift;
    int nt = wgid & ((1 << nt_shift) - 1);
    int m0 = mt * 64, n0 = nt * 64;

    int lr = lane & 15, lq = lane >> 4;
    float* Cf = (float*)Cptr;

    f32x4 acc[4];
#pragma unroll
    for (int j = 0; j < 4; ++j) acc[j] = (f32x4)(0.f);

#define STAGE(BI, KTI) do {                                                           \
    char* buf = lds + (BI) * 16384;                                                   \
    int k0b = (KTI) << 7;                                                             \
    _Pragma("unroll")                                                                 \
    for (int i_ = 0; i_ < 2; ++i_) {                                                  \
        int L_ = tid + (i_ << 8);                                                     \
        int row_ = L_ >> 3, c_ = L_ & 7;                                              \
        glds16((const char*)Ah + (size_t)(m0 + row_) * (K * 2) + k0b + ((c_ ^ (row_ & 7)) << 4), \
               buf + (L_ << 4));                                                      \
    }                                                                                 \
    _Pragma("unroll")                                                                 \
    for (int i_ = 0; i_ < 2; ++i_) {                                                  \
        int L_ = tid + (i_ << 8);                                                     \
        int row_ = L_ >> 3, c_ = L_ & 7;                                              \
        glds16((const char*)Bw + (size_t)(n0 + row_) * (K * 2) + k0b + ((c_ ^ (row_ & 7)) << 4), \
               buf + 8192 + (L_ << 4));                                               \
    }                                                                                 \
} while (0)

#define GMFMA(BI) do {                                                                \
    char* Abb = lds + (BI) * 16384;                                                   \
    char* Bbb = Abb + 8192;                                                           \
    _Pragma("unroll")                                                                 \
    for (int s_ = 0; s_ < 2; ++s_) {                                                  \
        int chunk_ = (s_ << 2) + lq;                                                  \
        int arow_ = (wid << 4) + lr;                                                  \
        bf16x8 af_ = *(bf16x8*)(Abb + arow_ * 128 + ((chunk_ ^ (arow_ & 7)) << 4));   \
        _Pragma("unroll")                                                             \
        for (int j_ = 0; j_ < 4; ++j_) {                                              \
            int brow_ = (j_ << 4) + lr;                                               \
            bf16x8 bf_ = *(bf16x8*)(Bbb + brow_ * 128 + ((chunk_ ^ (brow_ & 7)) << 4)); \
            acc[j_] = __builtin_amdgcn_mfma_f32_16x16x32_bf16(af_, bf_, acc[j_], 0, 0, 0); \
        }                                                                             \
    }                                                                                 \
} while (0)

    STAGE(0, 0);
    if (KT > 1) STAGE(1, 1);
#pragma unroll
    for (int kt = 0; kt < KT; ++kt) {
        if (kt + 1 < KT) {
            asm volatile("s_waitcnt vmcnt(4)" ::: "memory");
        } else {
            asm volatile("s_waitcnt vmcnt(0)" ::: "memory");
        }
        __builtin_amdgcn_s_barrier();
        __builtin_amdgcn_sched_barrier(0);
        if (kt + 2 < KT) STAGE((kt + 2) % 3, kt + 2);
        GMFMA(kt % 3);
        __builtin_amdgcn_sched_barrier(0);
    }

    {
        float s = 0.f;
#pragma unroll
        for (int v = 0; v < 6; ++v) {
            float x = wview[v];
            s += (x > 20.f) ? x : log1pf(expf(x));
        }
        float f = s / fmaxf(s, 1e-6f);
        int mb = m0 + (wid << 4) + (lq << 2);
#pragma unroll
        for (int j = 0; j < 4; ++j) {
            int n = n0 + (j << 4) + lr;
            float bn = bias[n];
            if (mb + 4 <= M) {
                float4 o;
                float* oo = (float*)&o;
#pragma unroll
                for (int e = 0; e < 4; ++e)
                    oo[e] = acc[j][e] + f * (bn + resid[(size_t)(mb + e) * 256 + n]);
                *(float4*)(Cf + (size_t)n * M + mb) = o;
            } else {
#pragma unroll
                for (int e = 0; e < 4; ++e) {
                    int m = mb + e;
                    if (m < M) Cf[(size_t)n * M + m] = acc[j][e] + f * (bn + resid[(size_t)m * 256 + n]);
                }
            }
        }
    }
#undef STAGE
#undef GMFMA
}

// ---------------- qout GEMM body: fp32 A reg-staged (64x64, 2-stage) ----------------
template <int KT>
__device__ __forceinline__ void gemm_f32A(char* base0, char* base1,
                                          const float* __restrict__ Af,
                                          const unsigned short* __restrict__ Bw,
                                          const float* __restrict__ bias,
                                          float* __restrict__ Cf,
                                          int M, int nt_shift, int bid, int nwg) {
    constexpr int K = KT * 64;
    int tid = threadIdx.x;
    int wid = tid >> 6, lane = tid & 63;

    int qd = nwg >> 3, r = nwg & 7;
    int xcd = bid & 7, seq = bid >> 3;
    int wgid = (xcd < r) ? (xcd * (qd + 1) + seq) : (r * (qd + 1) + (xcd - r) * qd + seq);
    int mt = wgid >> nt_shift;
    int nt = wgid & ((1 << nt_shift) - 1);
    int m0 = mt * 64, n0 = nt * 64;

    int lr = lane & 15, lq = lane >> 4;
    int arow_s = tid >> 4;
    int ac4 = tid & 15;

    f32x4 acc[4];
#pragma unroll
    for (int j = 0; j < 4; ++j) acc[j] = (f32x4)(0.f);

    float4 aF[2][4];
    uint4  bR[2][2];
    const float4 zf4 = make_float4(0.f, 0.f, 0.f, 0.f);

#define QLOADG(S, KTI) do {                                                           \
    int k0 = (KTI) << 6;                                                              \
    _Pragma("unroll")                                                                 \
    for (int p_ = 0; p_ < 4; ++p_) {                                                  \
        int row_ = p_ * 16 + arow_s;                                                  \
        bool av_ = (m0 + row_) < M;                                                   \
        aF[S][p_] = av_ ? *(const float4*)(Af + (size_t)(m0 + row_) * K + k0 + ac4 * 4) : zf4; \
    }                                                                                 \
    _Pragma("unroll")                                                                 \
    for (int i_ = 0; i_ < 2; ++i_) {                                                  \
        int s_ = tid + (i_ << 8);                                                     \
        int row_ = s_ >> 3, c_ = s_ & 7;                                              \
        bR[S][i_] = *(const uint4*)(Bw + (size_t)(n0 + row_) * K + k0 + c_ * 8);      \
    }                                                                                 \
} while (0)

#define QTOLDS(S, PB) do {                                                            \
    char* Abb = (PB) ? base1 : base0;                                                 \
    _Pragma("unroll")                                                                 \
    for (int p_ = 0; p_ < 4; ++p_) {                                                  \
        int row_ = p_ * 16 + arow_s;                                                  \
        const float* f_ = (const float*)&aF[S][p_];                                   \
        uint2 w_;                                                                     \
        w_.x = f2bf(f_[0]) | (f2bf(f_[1]) << 16);                                     \
        w_.y = f2bf(f_[2]) | (f2bf(f_[3]) << 16);                                     \
        int byte_ = row_ * 128 + (((ac4 >> 1) ^ (row_ & 7)) << 4) + ((ac4 & 1) << 3); \
        *(uint2*)(Abb + byte_) = w_;                                                  \
    }                                                                                 \
    char* Bbb = Abb + 8192;                                                           \
    _Pragma("unroll")                                                                 \
    for (int i_ = 0; i_ < 2; ++i_) {                                                  \
        int s_ = tid + (i_ << 8);                                                     \
        int row_ = s_ >> 3, c_ = s_ & 7;                                              \
        *(uint4*)(Bbb + row_ * 128 + ((c_ ^ (row_ & 7)) << 4)) = bR[S][i_];           \
    }                                                                                 \
} while (0)

#define QMFMAS(PB) do {                                                               \
    char* Abb = (PB) ? base1 : base0;                                                 \
    char* Bbb = Abb + 8192;                                                           \
    _Pragma("unroll")                                                                 \
    for (int s_ = 0; s_ < 2; ++s_) {                                                  \
        int chunk_ = (s_ << 2) + lq;                                                  \
        int arow_ = (wid << 4) + lr;                                                  \
        bf16x8 af_ = *(bf16x8*)(Abb + arow_ * 128 + ((chunk_ ^ (arow_ & 7)) << 4));   \
        _Pragma("unroll")                                                             \
        for (int j_ = 0; j_ < 4; ++j_) {                                              \
            int brow_ = (j_ << 4) + lr;                                               \
            bf16x8 bf_ = *(bf16x8*)(Bbb + brow_ * 128 + ((chunk_ ^ (brow_ & 7)) << 4)); \
            acc[j_] = __builtin_amdgcn_mfma_f32_16x16x32_bf16(af_, bf_, acc[j_], 0, 0, 0); \
        }                                                                             \
    }                                                                                 \
} while (0)

    QLOADG(0, 0);
#pragma unroll
    for (int kt = 0; kt < KT; ++kt) {
        if (kt + 1 < KT) QLOADG((kt + 1) & 1, kt + 1);
        QTOLDS(kt & 1, kt & 1);
        __builtin_amdgcn_sched_barrier(0);
        asm volatile("s_waitcnt lgkmcnt(0)" ::: "memory");
        __builtin_amdgcn_s_barrier();
        __builtin_amdgcn_sched_barrier(0);
        QMFMAS(kt & 1);
    }

    int mb = m0 + (wid << 4) + (lq << 2);
#pragma unroll
    for (int j = 0; j < 4; ++j) {
        int n = n0 + (j << 4) + lr;
        if (n >= 96) continue;
        float bn = bias[n];
#pragma unroll
        for (int e = 0; e < 4; ++e) {
            int m = mb + e;
            if (m < M) Cf[(size_t)m * 96 + n] = acc[j][e] + bn;
        }
    }
#undef QLOADG
#undef QTOLDS
#undef QMFMAS
}

// val (916 blocks, fp32-A glds) + qout (314 blocks, reg-staged) in one launch
__global__ __launch_bounds__(256, 3) void dual_gemm(const float* __restrict__ lt,
                                                    const unsigned short* __restrict__ W2b,
                                                    const float* __restrict__ vpb,
                                                    unsigned short* __restrict__ valB,
                                                    const float* __restrict__ bqq,
                                                    const unsigned short* __restrict__ WQb,
                                                    const float* __restrict__ bqp,
                                                    float* __restrict__ qout) {
    __shared__ char lds[49152];
    if (blockIdx.x < 916)
        gemm_glds32A<12>(lds, lt, W2b, vpb, valB, 14652, blockIdx.x, 916);
    else
        gemm_f32A<4>(lds, lds + 16384, bqq, WQb, bqp, qout, Q_TOT, 1, blockIdx.x - 916, 314);
}

__global__ __launch_bounds__(256, 3) void out_gemm(const unsigned short* __restrict__ sampavgB,
                                                   const unsigned short* __restrict__ opwb,
                                                   const float* __restrict__ opb,
                                                   const float* __restrict__ bqq,
                                                   const float* __restrict__ wview,
                                                   float* __restrict__ out) {
    __shared__ char lds[49152];
    gemm_glds<1, 4>(lds, sampavgB, opwb, opb, bqq, wview,
                    (void*)out, Q_TOT, 2, blockIdx.x, gridDim.x);
}

// ---------------- deformable sampling: bf16 table, dwordx2 gathers ----------------
__global__ __launch_bounds__(256) void sample_kernel(const unsigned short* __restrict__ valB,
                                                     const float* __restrict__ ref2d,
                                                     const float* __restrict__ qout,
                                                     const float* __restrict__ vwn,
                                                     unsigned short* __restrict__ sampavgB) {
    __shared__ uint4  sOff[4 * 240];
    __shared__ float4 sW[4 * 240];
    __shared__ float4 sAt[4 * 8];
    __shared__ float  sVw[8];
    int tid = threadIdx.x;
    int qb = blockIdx.x * 4;

    if (tid < 32) {
        int ql = tid >> 3, h = tid & 7;
        const float* qo = qout + (size_t)(qb + ql) * 96 + 64 + h * 4;
        float a0 = qo[0], a1 = qo[1], a2 = qo[2], a3 = qo[3];
        float mx = fmaxf(fmaxf(a0, a1), fmaxf(a2, a3));
        float e0 = __expf(a0 - mx), e1 = __expf(a1 - mx), e2 = __expf(a2 - mx), e3 = __expf(a3 - mx);
        float inv = 1.0f / (e0 + e1 + e2 + e3);
        sAt[ql * 8 + h] = make_float4(e0 * inv, e1 * inv, e2 * inv, e3 * inv);
        if (tid < 8) sVw[tid] = vwn[tid < 6 ? tid : 0];
    }
    __syncthreads();

#pragma unroll
    for (int t = tid; t < 768; t += 256) {
        int ql = t / 192;
        int rem = t - ql * 192;
        int v = rem >> 5;
        int h = (rem >> 2) & 7;
        int p = rem & 3;
        int q = qb + ql;
        const float* qo = qout + (size_t)q * 96;
        float ox = qo[h * 8 + 2 * p];
        float oy = qo[h * 8 + 2 * p + 1];
        float at = ((const float*)&sAt[ql * 8 + h])[p];
        float scale = at * sVw[v];

        float rx = ref2d[(size_t)(v * Q_TOT + q) * 2 + 0];
        float ry = ref2d[(size_t)(v * Q_TOT + q) * 2 + 1];
        float x = rx * 66.0f + ox - 0.5f;
        float y = ry * 37.0f + oy - 0.5f;
        float xf = floorf(x), yf = floorf(y);
        float fx = x - xf, fy = y - yf;
        int xi = (int)xf, yi = (int)yf;

        float cw[4] = { (1.f - fx) * (1.f - fy), fx * (1.f - fy), (1.f - fx) * fy, fx * fy };
        unsigned off[4];
#pragma unroll
        for (int cyi = 0; cyi < 2; ++cyi) {
#pragma unroll
            for (int cxi = 0; cxi < 2; ++cxi) {
                int cx = xi + cxi, cy = yi + cyi;
                bool ok = (cx >= 0) && (cx < WP_) && (cy >= 0) && (cy < HP_);
                int ccx = cx < 0 ? 0 : (cx > WP_ - 1 ? WP_ - 1 : cx);
                int ccy = cy < 0 ? 0 : (cy > HP_ - 1 ? HP_ - 1 : cy);
                int c_ = cyi * 2 + cxi;
                off[c_] = (unsigned)((v * NTOK + ccy * WP_ + ccx) << 9);
                cw[c_] = ok ? cw[c_] * scale : 0.f;
            }
        }
        int slot = ql * 240 + v * 40 + h * 5 + p;
        sOff[slot] = make_uint4(off[0], off[1], off[2], off[3]);
        sW[slot]   = make_float4(cw[0], cw[1], cw[2], cw[3]);
    }
    __syncthreads();

    int ql = tid >> 6;
    int lane = tid & 63;
    int h = lane >> 3, d4 = (lane & 7) << 2;
    unsigned coff = (unsigned)((h * 32 + d4) << 1);
    const char* vbase = (const char*)valB;
    float acc0 = 0.f, acc1 = 0.f, acc2 = 0.f, acc3 = 0.f;
#pragma unroll
    for (int v = 0; v < NVIEW; ++v) {
#pragma unroll
        for (int p = 0; p < 4; ++p) {
            int slot = ql * 240 + v * 40 + h * 5 + p;
            uint4 off = sOff[slot];
            float4 w = sW[slot];
            uint2 r0 = *(const uint2*)(vbase + (off.x + coff));
            uint2 r1 = *(const uint2*)(vbase + (off.y + coff));
            uint2 r2 = *(const uint2*)(vbase + (off.z + coff));
            uint2 r3 = *(const uint2*)(vbase + (off.w + coff));
            float g0, g1;
            g0 = __builtin_bit_cast(float, r0.x << 16); g1 = __builtin_bit_cast(float, r0.x & 0xFFFF0000u);
            acc0 += w.x * g0; acc1 += w.x * g1;
            g0 = __builtin_bit_cast(float, r0.y << 16); g1 = __builtin_bit_cast(float, r0.y & 0xFFFF0000u);
            acc2 += w.x * g0; acc3 += w.x * g1;
            g0 = __builtin_bit_cast(float, r1.x << 16); g1 = __builtin_bit_cast(float, r1.x & 0xFFFF0000u);
            acc0 += w.y * g0; acc1 += w.y * g1;
            g0 = __builtin_bit_cast(float, r1.y << 16); g1 = __builtin_bit_cast(float, r1.y & 0xFFFF0000u);
            acc2 += w.y * g0; acc3 += w.y * g1;
            g0 = __builtin_bit_cast(float, r2.x << 16); g1 = __builtin_bit_cast(float, r2.x & 0xFFFF0000u);
            acc0 += w.z * g0; acc1 += w.z * g1;
            g0 = __builtin_bit_cast(float, r2.y << 16); g1 = __builtin_bit_cast(float, r2.y & 0xFFFF0000u);
            acc2 += w.z * g0; acc3 += w.z * g1;
            g0 = __builtin_bit_cast(float, r3.x << 16); g1 = __builtin_bit_cast(float, r3.x & 0xFFFF0000u);
            acc0 += w.w * g0; acc1 += w.w * g1;
            g0 = __builtin_bit_cast(float, r3.y << 16); g1 = __builtin_bit_cast(float, r3.y & 0xFFFF0000u);
            acc2 += w.w * g0; acc3 += w.w * g1;
        }
    }
    int q = qb + ql;
    unsigned u0 = f2bf(acc0) | (f2bf(acc1) << 16);
    unsigned u1 = f2bf(acc2) | (f2bf(acc3) << 16);
    *(uint2*)(sampavgB + (size_t)q * CC_ + h * 32 + d4) = make_uint2(u0, u1);
}

extern "C" void kernel_launch(void* const* d_in, const int* in_sizes, int n_in,
                              void* d_out, int out_size, void* d_ws, size_t ws_size,
                              hipStream_t stream) {
    const float* lt   = (const float*)d_in[0];
    const float* l2i  = (const float*)d_in[1];
    const float* proj = (const float*)d_in[2];
    const float* bqq  = (const float*)d_in[3];
    const float* wv   = (const float*)d_in[4];
    const float* vpw  = (const float*)d_in[5];
    const float* vpb  = (const float*)d_in[6];
    const float* sow  = (const float*)d_in[7];
    const float* sob  = (const float*)d_in[8];
    const float* aww  = (const float*)d_in[9];
    const float* awb  = (const float*)d_in[10];
    const float* opw  = (const float*)d_in[11];
    const float* opb  = (const float*)d_in[12];
    float* out = (float*)d_out;

    char* ws = (char*)d_ws;
    unsigned short* W2b   = (unsigned short*)(ws);             // 393216
    unsigned short* opwb  = (unsigned short*)(ws + 393216);    // 131072
    unsigned short* WQb   = (unsigned short*)(ws + 524288);    // 65536
    float*          bqp   = (float*)(ws + 589824);             // 512
    float*          vwn   = (float*)(ws + 590336);             // 512
    float*          ref2d = (float*)(ws + 590848);             // 480000
    float*          qout  = (float*)(ws + 1070848);            // 3840000 -> ends 4910848
    unsigned short* valB  = (unsigned short*)(ws + 4910848);   // 7501824 -> ends 12412672
    unsigned short* sampavgB = (unsigned short*)(ws + 12412672); // 5120000 -> ends 17532672

    hipLaunchKernelGGL(prep_all, dim3(1163), dim3(256), 0, stream,
                       vpw, proj, opw, l2i, sow, sob, aww, awb, wv,
                       W2b, opwb, ref2d, WQb, bqp, vwn);
    hipLaunchKernelGGL(dual_gemm, dim3(1230), dim3(256), 0, stream,
                       lt, W2b, vpb, valB, bqq, WQb, bqp, qout);
    hipLaunchKernelGGL(sample_kernel, dim3(Q_TOT / 4), dim3(256), 0, stream,
                       valB, ref2d, qout, vwn, sampavgB);
    hipLaunchKernelGGL(out_gemm, dim3(628), dim3(256), 0, stream,
                       sampavgB, opwb, opb, bqq, wv, out);
}